// Round 4
// baseline (3307.114 us; speedup 1.0000x reference)
//
#include <hip/hip_runtime.h>

#define N_NODES 100000
#define D 128
#define N_ADJ 6
#define NNZ 600000
#define N_HOPS 7
#define EDGES_TOTAL (N_ADJ * NNZ)

#define B_SHIFT 7
#define B_ROWS 128
#define NB ((N_NODES + B_ROWS - 1) / B_ROWS)   // 782 buckets
#define SLAB 5632                               // capacity per bucket (mean 4604 + 15 sigma)
#define CHUNK 4096                              // edges per passA workgroup
#define EPT 16                                  // edges per thread (CHUNK/256)

// ---------------------------------------------------------------------------
// Phase 0: mix = softmax(linear_weight), 7 elements
// ---------------------------------------------------------------------------
__global__ void softmax_mix_kernel(const float* __restrict__ lw,
                                   float* __restrict__ mix) {
    if (threadIdx.x == 0) {
        float m = lw[0];
        for (int i = 1; i < N_HOPS; ++i) m = fmaxf(m, lw[i]);
        float e[N_HOPS];
        float s = 0.f;
        for (int i = 0; i < N_HOPS; ++i) { e[i] = __expf(lw[i] - m); s += e[i]; }
        float inv = 1.f / s;
        for (int i = 0; i < N_HOPS; ++i) mix[i] = e[i] * inv;
    }
}

// ---------------------------------------------------------------------------
// bpos[b] = b*SLAB  (bucket write cursors; fixed-capacity slabs, no scan)
// ---------------------------------------------------------------------------
__global__ void bpos_init_kernel(int* __restrict__ bpos) {
    int b = blockIdx.x * 256 + threadIdx.x;
    if (b < NB) bpos[b] = b * SLAB;
}

// ---------------------------------------------------------------------------
// Pass A: LDS-aggregated bucket scatter. Each WG stages a 4096-edge chunk in
// LDS grouped by bucket (row>>7), then flushes contiguous per-bucket runs to
// the fixed-slab tmp array. Payload: {rowLocal(7b)<<25 | col, premixed val}.
// ---------------------------------------------------------------------------
__global__ __launch_bounds__(256) void bucket_scatter_kernel(
    const int* __restrict__ rows, const int* __restrict__ cols,
    const float* __restrict__ vals, const float* __restrict__ mix,
    int* __restrict__ bpos, int2* __restrict__ tmp) {
    __shared__ int cnt[NB];
    __shared__ int off[NB];
    __shared__ int gbase[NB];
    __shared__ int scanbuf[256];
    __shared__ int2 stage[CHUNK];

    int base = blockIdx.x * CHUNK;
    int t = threadIdx.x;

    for (int i = t; i < NB; i += 256) cnt[i] = 0;
    __syncthreads();

    // Phase 1: count + capture slots
    int myRow[EPT];
    int mySlot[EPT];
    #pragma unroll
    for (int k = 0; k < EPT; ++k) {
        int e = base + k * 256 + t;
        if (e < EDGES_TOTAL) {
            int r = rows[e];
            myRow[k] = r;
            mySlot[k] = atomicAdd(&cnt[r >> B_SHIFT], 1);
        } else {
            myRow[k] = -1;
            mySlot[k] = 0;
        }
    }
    __syncthreads();

    // Exclusive scan of cnt[0..NB) (each thread owns 4 buckets)
    int i0 = t * 4;
    int c4[4];
    int s = 0;
    #pragma unroll
    for (int k = 0; k < 4; ++k) {
        int i = i0 + k;
        c4[k] = (i < NB) ? cnt[i] : 0;
        s += c4[k];
    }
    scanbuf[t] = s;
    __syncthreads();
    for (int o = 1; o < 256; o <<= 1) {
        int u = 0;
        if (t >= o) u = scanbuf[t - o];
        __syncthreads();
        if (t >= o) scanbuf[t] += u;
        __syncthreads();
    }
    int run = scanbuf[t] - s;
    #pragma unroll
    for (int k = 0; k < 4; ++k) {
        int i = i0 + k;
        if (i < NB) off[i] = run;
        run += c4[k];
    }
    // Reserve global slab ranges (one atomic per bucket per chunk)
    for (int i = t; i < NB; i += 256)
        gbase[i] = atomicAdd(&bpos[i], cnt[i]);
    __syncthreads();

    // Phase 2: place edges into LDS stage, bucket-grouped
    #pragma unroll
    for (int k = 0; k < EPT; ++k) {
        int e = base + k * 256 + t;
        int r = myRow[k];
        if (r >= 0) {
            int b = r >> B_SHIFT;
            int rl = r & (B_ROWS - 1);
            int a = e / NNZ;
            float v = vals[e] * mix[a + 1];
            int packed = (rl << 25) | cols[e];
            stage[off[b] + mySlot[k]] = make_int2(packed, __float_as_int(v));
        }
    }
    __syncthreads();

    // Phase 3: flush contiguous per-bucket runs to global slabs
    for (int i = t; i < NB; i += 256) {
        int c = cnt[i];
        int g = gbase[i];
        int o = off[i];
        for (int j = 0; j < c; ++j) tmp[g + j] = stage[o + j];
    }
}

// ---------------------------------------------------------------------------
// Bucket accumulate (pull): one WG per bucket. LDS f32 tile [128 rows x 128],
// plane-swizzled so lane l always hits bank l: element c of a row is stored
// at (c&3)*32 + (c>>2). Self-term (mix0*input) initializes the tile; each
// half-wave (32 lanes) then processes bucket edges, gathering input[col]
// as float4 and ds_add-ing into the tile. Tile written to rep once at end.
// No global float atomics, no CSR ordering needed.
// ---------------------------------------------------------------------------
__global__ __launch_bounds__(256) void bucket_accum_kernel(
    const int* __restrict__ bpos, const int2* __restrict__ tmp,
    const float4* __restrict__ in4, float4* __restrict__ rep4,
    const float* __restrict__ mix) {
    __shared__ float tile[B_ROWS * D];   // 64 KB

    int b = blockIdx.x;
    int t = threadIdx.x;
    int rbase = b << B_SHIFT;
    int l = t & 31;
    float m0 = mix[0];

    // init tile with mix0 * input (plane-swizzled store, bank l for lane l)
    for (int r = t >> 5; r < B_ROWS; r += 8) {
        int row = rbase + r;
        float4 v = make_float4(0.f, 0.f, 0.f, 0.f);
        if (row < N_NODES) v = in4[row * 32 + l];
        int bse = r * D + l;
        tile[bse +  0] = m0 * v.x;
        tile[bse + 32] = m0 * v.y;
        tile[bse + 64] = m0 * v.z;
        tile[bse + 96] = m0 * v.w;
    }
    __syncthreads();

    int start = b * SLAB;
    int end = bpos[b];        // final cursor after passA = start + count
    int hw = t >> 5;          // half-wave id, 0..7

    for (int j0 = start + hw * 4; j0 < end; j0 += 32) {
        int n = end - j0; if (n > 4) n = 4;
        int2 e[4]; float4 y[4]; int rl[4];
        #pragma unroll
        for (int u = 0; u < 4; ++u)
            if (u < n) e[u] = tmp[j0 + u];
        #pragma unroll
        for (int u = 0; u < 4; ++u)
            if (u < n) {
                int col = e[u].x & 0x01FFFFFF;
                rl[u] = ((unsigned)e[u].x) >> 25;
                y[u] = in4[col * 32 + l];
            }
        #pragma unroll
        for (int u = 0; u < 4; ++u)
            if (u < n) {
                float v = __int_as_float(e[u].y);
                int bse = rl[u] * D + l;
                atomicAdd(&tile[bse +  0], v * y[u].x);
                atomicAdd(&tile[bse + 32], v * y[u].y);
                atomicAdd(&tile[bse + 64], v * y[u].z);
                atomicAdd(&tile[bse + 96], v * y[u].w);
            }
    }
    __syncthreads();

    // write tile -> rep (un-swizzle: gather the 4 planes, store float4)
    for (int r = t >> 5; r < B_ROWS; r += 8) {
        int row = rbase + r;
        if (row >= N_NODES) continue;
        int bse = r * D + l;
        float4 o = make_float4(tile[bse], tile[bse + 32],
                               tile[bse + 64], tile[bse + 96]);
        rep4[row * 32 + l] = o;
    }
}

// ---------------------------------------------------------------------------
// Fallback path (tiny ws): rep = mix[0]*input, then atomic push-scatter
// ---------------------------------------------------------------------------
__global__ __launch_bounds__(256) void rep_init_kernel(
    const float4* __restrict__ in4, float4* __restrict__ rep4,
    const float* __restrict__ mix) {
    int i = blockIdx.x * blockDim.x + threadIdx.x;
    if (i >= N_NODES * D / 4) return;
    float m0 = mix[0];
    float4 v = in4[i];
    v.x *= m0; v.y *= m0; v.z *= m0; v.w *= m0;
    rep4[i] = v;
}

__global__ __launch_bounds__(256) void scatter_kernel(
    const int* __restrict__ rows, const int* __restrict__ cols,
    const float* __restrict__ vals, const float4* __restrict__ in4,
    float* __restrict__ rep, const float* __restrict__ mix) {
    long long gid = (long long)blockIdx.x * blockDim.x + threadIdx.x;
    int e = (int)(gid >> 5);
    int l = (int)(gid & 31);
    if (e >= EDGES_TOTAL) return;
    int a = e / NNZ;
    int row = rows[e];
    int col = cols[e];
    float v = vals[e] * mix[a + 1];
    float4 x = in4[col * 32 + l];
    float* dst = rep + (long long)row * D + l * 4;
    atomicAdd(dst + 0, v * x.x);
    atomicAdd(dst + 1, v * x.y);
    atomicAdd(dst + 2, v * x.z);
    atomicAdd(dst + 3, v * x.w);
}

// ---------------------------------------------------------------------------
// out = rep @ W + bias. Register-blocked: 256 thr = 8 row-quads(8 rows) x 32
// col-groups(4 cols); each thread does 8 rows x 4 cols -> W read from LDS
// once per 8 rows (0.8 GB LDS traffic vs 6.4 GB for 1-row version).
// ---------------------------------------------------------------------------
__global__ __launch_bounds__(256) void gemm_kernel(
    const float4* __restrict__ rep4, const float4* __restrict__ w4,
    const float4* __restrict__ bias4, float4* __restrict__ out4) {
    __shared__ float4 Wlds[D * (D / 4)];   // [k][j4], 64 KB

    for (int idx = threadIdx.x; idx < D * (D / 4); idx += 256)
        Wlds[idx] = w4[idx];
    __syncthreads();

    int tc = threadIdx.x & 31;     // 4-col group
    int rg = threadIdx.x >> 5;     // 8-row group, 0..7
    int r0 = blockIdx.x * 64 + rg * 8;

    float4 acc[8];
    #pragma unroll
    for (int i = 0; i < 8; ++i) acc[i] = make_float4(0.f, 0.f, 0.f, 0.f);

    for (int k4 = 0; k4 < D / 4; ++k4) {
        float4 w0 = Wlds[(k4 * 4 + 0) * 32 + tc];
        float4 w1 = Wlds[(k4 * 4 + 1) * 32 + tc];
        float4 w2 = Wlds[(k4 * 4 + 2) * 32 + tc];
        float4 w3 = Wlds[(k4 * 4 + 3) * 32 + tc];
        #pragma unroll
        for (int i = 0; i < 8; ++i) {
            int row = r0 + i;
            int rowc = row < N_NODES ? row : N_NODES - 1;  // clamp, discard at store
            float4 a = rep4[rowc * 32 + k4];
            acc[i].x += a.x * w0.x + a.y * w1.x + a.z * w2.x + a.w * w3.x;
            acc[i].y += a.x * w0.y + a.y * w1.y + a.z * w2.y + a.w * w3.y;
            acc[i].z += a.x * w0.z + a.y * w1.z + a.z * w2.z + a.w * w3.z;
            acc[i].w += a.x * w0.w + a.y * w1.w + a.z * w2.w + a.w * w3.w;
        }
    }

    float4 bb = bias4[tc];
    #pragma unroll
    for (int i = 0; i < 8; ++i) {
        int row = r0 + i;
        if (row >= N_NODES) continue;
        float4 o = acc[i];
        o.x += bb.x; o.y += bb.y; o.z += bb.z; o.w += bb.w;
        out4[row * 32 + tc] = o;
    }
}

// ---------------------------------------------------------------------------
extern "C" void kernel_launch(void* const* d_in, const int* in_sizes, int n_in,
                              void* d_out, int out_size, void* d_ws, size_t ws_size,
                              hipStream_t stream) {
    const float* input         = (const float*)d_in[0];
    const int*   adj_rows      = (const int*)d_in[1];
    const int*   adj_cols      = (const int*)d_in[2];
    const float* adj_vals      = (const float*)d_in[3];
    const float* weight        = (const float*)d_in[4];
    const float* linear_weight = (const float*)d_in[5];
    const float* bias          = (const float*)d_in[6];

    float* out = (float*)d_out;                    // [N_NODES, D]
    float* rep = out + (size_t)N_NODES * D;        // [N_NODES, D]

    // tmp (bucket slabs) aliases the `out` region: 782*5632*8B = 35.2MB
    // <= 51.2MB; out is only written by the final gemm, after tmp's
    // lifetime (passA write -> bucket_accum read) ends.
    int2* tmp = (int2*)out;

    // workspace: mix + bucket cursors only
    char* ws = (char*)d_ws;
    float* mix  = (float*)ws;                      ws += 32;
    int*   bpos = (int*)ws;                        ws += sizeof(int) * (NB + 2);
    size_t needed = (size_t)(ws - (char*)d_ws);

    softmax_mix_kernel<<<1, 64, 0, stream>>>(linear_weight, mix);

    if (ws_size >= needed) {
        bpos_init_kernel<<<(NB + 255) / 256, 256, 0, stream>>>(bpos);
        {
            int blocks = (EDGES_TOTAL + CHUNK - 1) / CHUNK;
            bucket_scatter_kernel<<<blocks, 256, 0, stream>>>(
                adj_rows, adj_cols, adj_vals, mix, bpos, tmp);
        }
        bucket_accum_kernel<<<NB, 256, 0, stream>>>(
            bpos, tmp, (const float4*)input, (float4*)rep, mix);
    } else {
        {
            int total = N_NODES * D / 4;
            int blocks = (total + 255) / 256;
            rep_init_kernel<<<blocks, 256, 0, stream>>>(
                (const float4*)input, (float4*)rep, mix);
        }
        {
            long long threads = (long long)EDGES_TOTAL * 32;
            int blocks = (int)((threads + 255) / 256);
            scatter_kernel<<<blocks, 256, 0, stream>>>(
                adj_rows, adj_cols, adj_vals, (const float4*)input, rep, mix);
        }
    }

    {
        int blocks = (N_NODES + 63) / 64;
        gemm_kernel<<<blocks, 256, 0, stream>>>(
            (const float4*)rep, (const float4*)weight,
            (const float4*)bias, (float4*)out);
    }
}